// Round 1
// baseline (247.192 us; speedup 1.0000x reference)
//
#include <hip/hip_runtime.h>

typedef __attribute__((ext_vector_type(8))) short short8;
typedef __attribute__((ext_vector_type(4))) float f32x4;

#define T_ 1024
#define D_ 64

__device__ __forceinline__ unsigned short f2bf(float f) {
    union { float f; unsigned u; } x; x.f = f;
    unsigned r = x.u + 0x7fffu + ((x.u >> 16) & 1u);
    return (unsigned short)(r >> 16);
}

// Stage a 64x64 fp32 tile (row-major, row stride 64) as bf16 into LDS with
// XOR swizzle: ushort index = (r*64+d) ^ ((r&7)<<3).  256 threads.
__device__ __forceinline__ void stage64x64(const float* __restrict__ src,
                                           unsigned short* dst, int tid) {
    const int r = tid >> 2, d0 = (tid & 3) * 16;
    const float* s = src + r * 64 + d0;
    __attribute__((aligned(16))) float tmp[16];
    *(float4*)(tmp + 0)  = *(const float4*)(s + 0);
    *(float4*)(tmp + 4)  = *(const float4*)(s + 4);
    *(float4*)(tmp + 8)  = *(const float4*)(s + 8);
    *(float4*)(tmp + 12) = *(const float4*)(s + 12);
    #pragma unroll
    for (int h = 0; h < 2; ++h) {
        short8 pk;
        #pragma unroll
        for (int i = 0; i < 8; ++i) pk[i] = (short)f2bf(tmp[h * 8 + i]);
        *(short8*)&dst[((r * 64 + d0 + h * 8) ^ ((r & 7) << 3))] = pk;
    }
}

// Stage a 64x64 fp32 tile TRANSPOSED (dst[d][s] = src[s][d]) as bf16, swizzled.
__device__ __forceinline__ void stage64x64T(const float* __restrict__ src,
                                            unsigned short* dst, int tid) {
    const int r = tid >> 2, d0 = (tid & 3) * 16;
    const float* s = src + r * 64 + d0;
    __attribute__((aligned(16))) float tmp[16];
    *(float4*)(tmp + 0)  = *(const float4*)(s + 0);
    *(float4*)(tmp + 4)  = *(const float4*)(s + 4);
    *(float4*)(tmp + 8)  = *(const float4*)(s + 8);
    *(float4*)(tmp + 12) = *(const float4*)(s + 12);
    #pragma unroll
    for (int i = 0; i < 16; ++i) {
        const int dd = d0 + i;
        dst[((dd * 64 + r) ^ ((dd & 7) << 3))] = f2bf(tmp[i]);
    }
}

__global__ __launch_bounds__(256, 2) void relattn(
    const float* __restrict__ qg, const float* __restrict__ kg,
    const float* __restrict__ vg, const float* __restrict__ embk,
    const float* __restrict__ embv,
    float* __restrict__ outg, float* __restrict__ attng)
{
    __shared__ __align__(16) unsigned short Qt[64 * 64];
    __shared__ __align__(16) unsigned short Kt[64 * 64];
    __shared__ __align__(16) unsigned short Vt[64 * 64];   // transposed: [d][s]
    __shared__ __align__(16) unsigned short Pt[64 * 64];
    __shared__ float biasS[64 * 34];
    __shared__ float wS[64 * 33];
    __shared__ float embvS[33 * 64];

    const int tid  = threadIdx.x;
    const int lane = tid & 63;
    const int wv   = tid >> 6;        // wave 0..3, owns rows 16*wv..+15
    const int g16  = lane >> 4;       // quad group 0..3
    const int l16  = lane & 15;
    const int rbase = wv * 16 + g16 * 4;   // first C-frag row for this lane

    const int bh = blockIdx.x >> 4;
    const int t0 = (blockIdx.x & 15) * 64;
    const long base = (long)bh * (T_ * D_);

    // ---------- prologue: stage Q, emb_v, zero w ----------
    stage64x64(qg + base + (long)t0 * D_, Qt, tid);
    for (int i = tid; i < 33 * 64; i += 256) embvS[i] = embv[i];
    for (int i = tid; i < 64 * 33; i += 256) wS[i] = 0.f;
    __syncthreads();

    // bias[r][j] = q_fp32[t0+r] . emb_k[j]   (fp32, from global — L2 hot)
    for (int p = tid; p < 64 * 33; p += 256) {
        const int r = p / 33, j = p - r * 33;
        const float* qr = qg + base + (long)(t0 + r) * D_;
        const float* er = embk + j * D_;
        float acc = 0.f;
        #pragma unroll
        for (int d = 0; d < 64; d += 4) {
            float4 a = *(const float4*)(qr + d);
            float4 b = *(const float4*)(er + d);
            acc += a.x * b.x + a.y * b.y + a.z * b.z + a.w * b.w;
        }
        biasS[r * 34 + j] = acc;
    }

    // hoist Q A-frags (rows 16*wv + l16, k = g16*8 + 32*ks)
    short8 qfrag[2];
    {
        const int r = wv * 16 + l16;
        const int sw = (r & 7) << 3;
        qfrag[0] = *(short8*)&Qt[((r * 64 + 0  + g16 * 8) ^ sw)];
        qfrag[1] = *(short8*)&Qt[((r * 64 + 32 + g16 * 8) ^ sw)];
    }
    __syncthreads();   // bias + staging visible

    // ---------- sweep 1: online row max / Z ----------
    float m_[4], Z_[4];
    #pragma unroll
    for (int j = 0; j < 4; ++j) { m_[j] = -1e30f; Z_[j] = 0.f; }

    for (int tile = 0; tile < 16; ++tile) {
        stage64x64(kg + base + (long)tile * 64 * D_, Kt, tid);
        __syncthreads();

        f32x4 acc[4];
        #pragma unroll
        for (int sc = 0; sc < 4; ++sc) {
            f32x4 a = {0.f, 0.f, 0.f, 0.f};
            #pragma unroll
            for (int ks = 0; ks < 2; ++ks) {
                const int r = sc * 16 + l16;
                short8 bf = *(short8*)&Kt[((r * 64 + ks * 32 + g16 * 8) ^ ((r & 7) << 3))];
                a = __builtin_amdgcn_mfma_f32_16x16x32_bf16(qfrag[ks], bf, a, 0, 0, 0);
            }
            acc[sc] = a;
        }
        #pragma unroll
        for (int j = 0; j < 4; ++j) {
            const int rl = rbase + j;
            const int tg = t0 + rl;
            float lv[4];
            float mx = -1e30f;
            #pragma unroll
            for (int sc = 0; sc < 4; ++sc) {
                const int sg = tile * 64 + sc * 16 + l16;
                int dc = sg - tg; dc = dc < -16 ? -16 : (dc > 16 ? 16 : dc);
                const float lg = 0.125f * (acc[sc][j] + biasS[rl * 34 + dc + 16]);
                lv[sc] = lg;
                mx = fmaxf(mx, lg);
            }
            #pragma unroll
            for (int o = 1; o < 16; o <<= 1) mx = fmaxf(mx, __shfl_xor(mx, o));
            const float mn = fmaxf(m_[j], mx);
            float sm = 0.f;
            #pragma unroll
            for (int sc = 0; sc < 4; ++sc) sm += __expf(lv[sc] - mn);
            #pragma unroll
            for (int o = 1; o < 16; o <<= 1) sm += __shfl_xor(sm, o);
            Z_[j] = Z_[j] * __expf(m_[j] - mn) + sm;
            m_[j] = mn;
        }
        __syncthreads();
    }

    float iZ[4];
    #pragma unroll
    for (int j = 0; j < 4; ++j) iZ[j] = 1.f / Z_[j];

    // ---------- sweep 2: attn write + PV + rel-v bookkeeping ----------
    f32x4 oacc[4];
    {
        f32x4 z = {0.f, 0.f, 0.f, 0.f};
        #pragma unroll
        for (int dc = 0; dc < 4; ++dc) oacc[dc] = z;
    }
    float p0[4]  = {0.f, 0.f, 0.f, 0.f};
    float p32[4] = {0.f, 0.f, 0.f, 0.f};
    float* attnB = attng + (long)bh * T_ * T_;

    for (int tile = 0; tile < 16; ++tile) {
        stage64x64 (kg + base + (long)tile * 64 * D_, Kt, tid);
        stage64x64T(vg + base + (long)tile * 64 * D_, Vt, tid);
        __syncthreads();

        // QK^T (recompute, deterministic == sweep 1)
        f32x4 acc[4];
        #pragma unroll
        for (int sc = 0; sc < 4; ++sc) {
            f32x4 a = {0.f, 0.f, 0.f, 0.f};
            #pragma unroll
            for (int ks = 0; ks < 2; ++ks) {
                const int r = sc * 16 + l16;
                short8 bf = *(short8*)&Kt[((r * 64 + ks * 32 + g16 * 8) ^ ((r & 7) << 3))];
                a = __builtin_amdgcn_mfma_f32_16x16x32_bf16(qfrag[ks], bf, a, 0, 0, 0);
            }
            acc[sc] = a;
        }
        // softmax finalize + attn store + P to LDS + w bookkeeping
        #pragma unroll
        for (int j = 0; j < 4; ++j) {
            const int rl = rbase + j;
            const int tg = t0 + rl;
            #pragma unroll
            for (int sc = 0; sc < 4; ++sc) {
                const int sl = sc * 16 + l16;
                const int sg = tile * 64 + sl;
                const int dsr = sg - tg;
                int dc = dsr < -16 ? -16 : (dsr > 16 ? 16 : dsr);
                const float lg = 0.125f * (acc[sc][j] + biasS[rl * 34 + dc + 16]);
                const float a = __expf(lg - m_[j]) * iZ[j];
                attnB[(long)tg * T_ + sg] = a;
                Pt[((rl * 64 + sl) ^ ((rl & 7) << 3))] = f2bf(a);
                if (dsr <= -16)      p0[j]  += a;
                else if (dsr >= 16)  p32[j] += a;
                else                 wS[rl * 33 + dsr + 16] = a;
            }
        }
        // PV: A = P (own wave's rows), B = V^T   (within-wave LDS dep — lgkmcnt)
        #pragma unroll
        for (int ks = 0; ks < 2; ++ks) {
            const int rp = wv * 16 + l16;
            short8 pa = *(short8*)&Pt[((rp * 64 + ks * 32 + g16 * 8) ^ ((rp & 7) << 3))];
            #pragma unroll
            for (int dc = 0; dc < 4; ++dc) {
                const int rv = dc * 16 + l16;
                short8 vb = *(short8*)&Vt[((rv * 64 + ks * 32 + g16 * 8) ^ ((rv & 7) << 3))];
                oacc[dc] = __builtin_amdgcn_mfma_f32_16x16x32_bf16(pa, vb, oacc[dc], 0, 0, 0);
            }
        }
        __syncthreads();
    }

    // ---------- w0 / w32 reduction ----------
    #pragma unroll
    for (int j = 0; j < 4; ++j) {
        float a0 = p0[j], a2 = p32[j];
        #pragma unroll
        for (int o = 1; o < 16; o <<= 1) {
            a0 += __shfl_xor(a0, o);
            a2 += __shfl_xor(a2, o);
        }
        if (l16 == 0) {
            wS[(rbase + j) * 33 + 0]  = a0;
            wS[(rbase + j) * 33 + 32] = a2;
        }
    }
    __syncthreads();

    // ---------- epilogue: out = PV + sum_j w[t][j]*emb_v[j] ----------
    #pragma unroll
    for (int j = 0; j < 4; ++j) {
        const int rl = rbase + j;
        const int tg = t0 + rl;
        float vals[4];
        #pragma unroll
        for (int dc = 0; dc < 4; ++dc) vals[dc] = oacc[dc][j];
        for (int jj = 0; jj < 33; ++jj) {
            const float wvv = wS[rl * 33 + jj];
            #pragma unroll
            for (int dc = 0; dc < 4; ++dc)
                vals[dc] += wvv * embvS[jj * 64 + dc * 16 + l16];
        }
        #pragma unroll
        for (int dc = 0; dc < 4; ++dc)
            outg[base + (long)tg * D_ + dc * 16 + l16] = vals[dc];
    }
}

extern "C" void kernel_launch(void* const* d_in, const int* in_sizes, int n_in,
                              void* d_out, int out_size, void* d_ws, size_t ws_size,
                              hipStream_t stream) {
    const float* q    = (const float*)d_in[0];
    const float* k    = (const float*)d_in[1];
    const float* v    = (const float*)d_in[2];
    const float* embk = (const float*)d_in[3];
    const float* embv = (const float*)d_in[4];
    float* out  = (float*)d_out;
    float* attn = out + (long)4 * 16 * 1024 * 64;   // out first, then attn
    relattn<<<dim3(4 * 16 * 16), dim3(256), 0, stream>>>(q, k, v, embk, embv, out, attn);
}

// Round 4
// 212.724 us; speedup vs baseline: 1.1620x; 1.1620x over previous
//
#include <hip/hip_runtime.h>

typedef __attribute__((ext_vector_type(8))) short short8;
typedef __attribute__((ext_vector_type(4))) float f32x4;

#define T_ 1024
#define D_ 64
#define CSC 0.18033688f   // 0.125 * log2(e)

static __device__ __forceinline__ unsigned short f2bf(float f) {
    union { float f; unsigned u; } x; x.f = f;
    unsigned r = x.u + 0x7fffu + ((x.u >> 16) & 1u);
    return (unsigned short)(r >> 16);
}
static __device__ __forceinline__ float fexp2(float x) {
    return __builtin_amdgcn_exp2f(fminf(x, 60.f));
}

// Stage a 64x64 fp32 tile (row stride 64) as bf16, XOR-swizzled rows.
static __device__ __forceinline__ void stage64x64(const float* __restrict__ src,
                                                  unsigned short* dst, int tid) {
    const int r = tid >> 2, d0 = (tid & 3) * 16;
    const float* s = src + r * 64 + d0;
    __attribute__((aligned(16))) float tmp[16];
    *(float4*)(tmp + 0)  = *(const float4*)(s + 0);
    *(float4*)(tmp + 4)  = *(const float4*)(s + 4);
    *(float4*)(tmp + 8)  = *(const float4*)(s + 8);
    *(float4*)(tmp + 12) = *(const float4*)(s + 12);
    #pragma unroll
    for (int h = 0; h < 2; ++h) {
        short8 pk;
        #pragma unroll
        for (int i = 0; i < 8; ++i) pk[i] = (short)f2bf(tmp[h * 8 + i]);
        *(short8*)&dst[((r * 64 + d0 + h * 8) ^ ((r & 7) << 3))] = pk;
    }
}

// Stage a 64x64 fp32 tile TRANSPOSED (dst[d][s]=src[s][d]) as bf16, swizzled.
// (round-1-validated pair with the PV read below)
static __device__ __forceinline__ void stage64x64T(const float* __restrict__ src,
                                                   unsigned short* dst, int tid) {
    const int r = tid >> 2, d0 = (tid & 3) * 16;
    const float* s = src + r * 64 + d0;
    __attribute__((aligned(16))) float tmp[16];
    *(float4*)(tmp + 0)  = *(const float4*)(s + 0);
    *(float4*)(tmp + 4)  = *(const float4*)(s + 4);
    *(float4*)(tmp + 8)  = *(const float4*)(s + 8);
    *(float4*)(tmp + 12) = *(const float4*)(s + 12);
    #pragma unroll
    for (int i = 0; i < 16; ++i) {
        const int dd = d0 + i;
        dst[((dd * 64 + r) ^ ((dd & 7) << 3))] = f2bf(tmp[i]);
    }
}

__global__ __launch_bounds__(256, 2) void relattn(
    const float* __restrict__ qg, const float* __restrict__ kg,
    const float* __restrict__ vg, const float* __restrict__ embk,
    const float* __restrict__ embv,
    float* __restrict__ outg, float* __restrict__ attng)
{
    __shared__ __align__(16) unsigned short Qt[64 * 64];
    __shared__ __align__(16) unsigned short Kt[64 * 64];
    __shared__ __align__(16) unsigned short Vt[64 * 64];   // transposed: [d][s]
    __shared__ __align__(16) unsigned short Pt[64 * 64];
    __shared__ float biasS[64 * 34];                       // fp32, pre-scaled by CSC
    __shared__ float wS[64 * 33];
    __shared__ float embvS[33 * 64];

    const int tid  = threadIdx.x;
    const int lane = tid & 63;
    const int wv   = tid >> 6;
    const int g16  = lane >> 4;
    const int l16  = lane & 15;
    const int rbase = wv * 16 + g16 * 4;

    const int bh = blockIdx.x >> 4;
    const int t0 = (blockIdx.x & 15) * 64;
    const int dtile = t0 >> 6;
    const long base = (long)bh * (T_ * D_);

    // ---------- prologue: stage Q, emb_v, zero w ----------
    stage64x64(qg + base + (long)t0 * D_, Qt, tid);
    for (int i = tid; i < 33 * 64; i += 256) embvS[i] = embv[i];
    for (int i = tid; i < 64 * 33; i += 256) wS[i] = 0.f;
    __syncthreads();

    // bias[r][j] = CSC * (q_fp32[t0+r] . emb_k[j])   (fp32 exact, R1-validated)
    for (int p = tid; p < 64 * 33; p += 256) {
        const int r = p / 33, j = p - r * 33;
        const float* qr = qg + base + (long)(t0 + r) * D_;
        const float* er = embk + j * D_;
        float acc = 0.f;
        #pragma unroll
        for (int d = 0; d < 64; d += 4) {
            float4 a = *(const float4*)(qr + d);
            float4 b = *(const float4*)(er + d);
            acc += a.x * b.x + a.y * b.y + a.z * b.z + a.w * b.w;
        }
        biasS[r * 34 + j] = acc * CSC;
    }

    // hoist Q A-frags (rows 16*wv + l16)
    short8 qfrag[2];
    {
        const int r = wv * 16 + l16;
        const int sw = (r & 7) << 3;
        qfrag[0] = *(short8*)&Qt[((r * 64 + 0  + g16 * 8) ^ sw)];
        qfrag[1] = *(short8*)&Qt[((r * 64 + 32 + g16 * 8) ^ sw)];
    }
    __syncthreads();   // bias visible (p-loop writes are cross-wave)

    // far-tile bias per own row
    float bias_m[4], bias_p[4];
    #pragma unroll
    for (int j = 0; j < 4; ++j) {
        bias_m[j] = biasS[(rbase + j) * 34 + 0];
        bias_p[j] = biasS[(rbase + j) * 34 + 32];
    }

    // ---------- sweep 1: Z only (no max, no shuffles in loop) ----------
    float zacc[4] = {0.f, 0.f, 0.f, 0.f};
    for (int tile = 0; tile < 16; ++tile) {
        stage64x64(kg + base + (long)tile * 64 * D_, Kt, tid);
        __syncthreads();

        f32x4 acc[4];
        #pragma unroll
        for (int sc = 0; sc < 4; ++sc) {
            f32x4 a = {0.f, 0.f, 0.f, 0.f};
            #pragma unroll
            for (int ks = 0; ks < 2; ++ks) {
                const int r = sc * 16 + l16;
                short8 bf = *(short8*)&Kt[((r * 64 + ks * 32 + g16 * 8) ^ ((r & 7) << 3))];
                a = __builtin_amdgcn_mfma_f32_16x16x32_bf16(qfrag[ks], bf, a, 0, 0, 0);
            }
            acc[sc] = a;
        }
        if (tile < dtile - 1) {
            #pragma unroll
            for (int j = 0; j < 4; ++j)
                #pragma unroll
                for (int sc = 0; sc < 4; ++sc)
                    zacc[j] += fexp2(fmaf(acc[sc][j], CSC, bias_m[j]));
        } else if (tile > dtile + 1) {
            #pragma unroll
            for (int j = 0; j < 4; ++j)
                #pragma unroll
                for (int sc = 0; sc < 4; ++sc)
                    zacc[j] += fexp2(fmaf(acc[sc][j], CSC, bias_p[j]));
        } else {
            #pragma unroll
            for (int j = 0; j < 4; ++j) {
                const int rl = rbase + j;
                const int tg = t0 + rl;
                #pragma unroll
                for (int sc = 0; sc < 4; ++sc) {
                    const int sg = tile * 64 + sc * 16 + l16;
                    int dsr = sg - tg;
                    int dc = dsr < -16 ? -16 : (dsr > 16 ? 16 : dsr);
                    const float b = biasS[rl * 34 + dc + 16];
                    zacc[j] += fexp2(fmaf(acc[sc][j], CSC, b));
                }
            }
        }
        __syncthreads();
    }
    float iZ[4];
    #pragma unroll
    for (int j = 0; j < 4; ++j) {
        float z = zacc[j];
        #pragma unroll
        for (int o = 1; o < 16; o <<= 1) z += __shfl_xor(z, o);
        iZ[j] = 1.f / z;
    }

    // ---------- sweep 2: attn write + PV + rel-v bookkeeping ----------
    f32x4 oacc[4];
    {
        f32x4 z = {0.f, 0.f, 0.f, 0.f};
        #pragma unroll
        for (int dc = 0; dc < 4; ++dc) oacc[dc] = z;
    }
    float ps0[4]  = {0.f, 0.f, 0.f, 0.f};
    float ps32[4] = {0.f, 0.f, 0.f, 0.f};
    float* attnB = attng + (long)bh * T_ * T_;

    for (int tile = 0; tile < 16; ++tile) {
        stage64x64 (kg + base + (long)tile * 64 * D_, Kt, tid);
        stage64x64T(vg + base + (long)tile * 64 * D_, Vt, tid);
        __syncthreads();

        f32x4 acc[4];
        #pragma unroll
        for (int sc = 0; sc < 4; ++sc) {
            f32x4 a = {0.f, 0.f, 0.f, 0.f};
            #pragma unroll
            for (int ks = 0; ks < 2; ++ks) {
                const int r = sc * 16 + l16;
                short8 bf = *(short8*)&Kt[((r * 64 + ks * 32 + g16 * 8) ^ ((r & 7) << 3))];
                a = __builtin_amdgcn_mfma_f32_16x16x32_bf16(qfrag[ks], bf, a, 0, 0, 0);
            }
            acc[sc] = a;
        }

        if (tile < dtile - 1) {
            #pragma unroll
            for (int j = 0; j < 4; ++j) {
                const int rl = rbase + j;
                const int tg = t0 + rl;
                #pragma unroll
                for (int sc = 0; sc < 4; ++sc) {
                    const int sl = sc * 16 + l16;
                    const float a = fexp2(fmaf(acc[sc][j], CSC, bias_m[j])) * iZ[j];
                    attnB[(long)tg * T_ + tile * 64 + sl] = a;
                    Pt[((rl * 64 + sl) ^ ((rl & 7) << 3))] = f2bf(a);
                    ps0[j] += a;
                }
            }
        } else if (tile > dtile + 1) {
            #pragma unroll
            for (int j = 0; j < 4; ++j) {
                const int rl = rbase + j;
                const int tg = t0 + rl;
                #pragma unroll
                for (int sc = 0; sc < 4; ++sc) {
                    const int sl = sc * 16 + l16;
                    const float a = fexp2(fmaf(acc[sc][j], CSC, bias_p[j])) * iZ[j];
                    attnB[(long)tg * T_ + tile * 64 + sl] = a;
                    Pt[((rl * 64 + sl) ^ ((rl & 7) << 3))] = f2bf(a);
                    ps32[j] += a;
                }
            }
        } else {
            #pragma unroll
            for (int j = 0; j < 4; ++j) {
                const int rl = rbase + j;
                const int tg = t0 + rl;
                #pragma unroll
                for (int sc = 0; sc < 4; ++sc) {
                    const int sl = sc * 16 + l16;
                    const int sg = tile * 64 + sl;
                    const int dsr = sg - tg;
                    int dc = dsr < -16 ? -16 : (dsr > 16 ? 16 : dsr);
                    const float b = biasS[rl * 34 + dc + 16];
                    const float a = fexp2(fmaf(acc[sc][j], CSC, b)) * iZ[j];
                    attnB[(long)tg * T_ + sg] = a;
                    Pt[((rl * 64 + sl) ^ ((rl & 7) << 3))] = f2bf(a);
                    if (dsr <= -16)      ps0[j]  += a;
                    else if (dsr >= 16)  ps32[j] += a;
                    else                 wS[rl * 33 + dsr + 16] = a;
                }
            }
        }

        // PV: A = P (own wave rows), B = V^T   (R1-validated pair, no xg)
        #pragma unroll
        for (int ks = 0; ks < 2; ++ks) {
            const int rp = wv * 16 + l16;
            short8 pa = *(short8*)&Pt[((rp * 64 + ks * 32 + g16 * 8) ^ ((rp & 7) << 3))];
            #pragma unroll
            for (int dc = 0; dc < 4; ++dc) {
                const int rv = dc * 16 + l16;
                short8 vb = *(short8*)&Vt[((rv * 64 + ks * 32 + g16 * 8) ^ ((rv & 7) << 3))];
                oacc[dc] = __builtin_amdgcn_mfma_f32_16x16x32_bf16(pa, vb, oacc[dc], 0, 0, 0);
            }
        }
        __syncthreads();
    }

    // ---------- boundary-bucket reduction ----------
    float w0r[4], w32r[4];
    #pragma unroll
    for (int j = 0; j < 4; ++j) {
        float a0 = ps0[j], a2 = ps32[j];
        #pragma unroll
        for (int o = 1; o < 16; o <<= 1) {
            a0 += __shfl_xor(a0, o);
            a2 += __shfl_xor(a2, o);
        }
        w0r[j] = a0; w32r[j] = a2;
    }
    __syncthreads();   // wS interior writes visible to epilogue readers

    // ---------- epilogue: out = PV + sum_j w[t][j]*emb_v[j] ----------
    float vals[4][4];
    #pragma unroll
    for (int j = 0; j < 4; ++j)
        #pragma unroll
        for (int dc = 0; dc < 4; ++dc)
            vals[j][dc] = oacc[dc][j]
                        + w0r[j]  * embvS[0 * 64  + dc * 16 + l16]
                        + w32r[j] * embvS[32 * 64 + dc * 16 + l16];
    for (int jj = 1; jj < 32; ++jj) {
        float e[4];
        #pragma unroll
        for (int dc = 0; dc < 4; ++dc) e[dc] = embvS[jj * 64 + dc * 16 + l16];
        #pragma unroll
        for (int j = 0; j < 4; ++j) {
            const float w = wS[(rbase + j) * 33 + jj];
            #pragma unroll
            for (int dc = 0; dc < 4; ++dc) vals[j][dc] += w * e[dc];
        }
    }
    #pragma unroll
    for (int j = 0; j < 4; ++j) {
        const int tg = t0 + rbase + j;
        #pragma unroll
        for (int dc = 0; dc < 4; ++dc)
            outg[base + (long)tg * D_ + dc * 16 + l16] = vals[j][dc];
    }
}

extern "C" void kernel_launch(void* const* d_in, const int* in_sizes, int n_in,
                              void* d_out, int out_size, void* d_ws, size_t ws_size,
                              hipStream_t stream) {
    const float* q    = (const float*)d_in[0];
    const float* k    = (const float*)d_in[1];
    const float* v    = (const float*)d_in[2];
    const float* embk = (const float*)d_in[3];
    const float* embv = (const float*)d_in[4];
    float* out  = (float*)d_out;
    float* attn = out + (long)4 * 16 * 1024 * 64;
    relattn<<<dim3(4 * 16 * 16), dim3(256), 0, stream>>>(q, k, v, embk, embv, out, attn);
}